// Round 3
// baseline (346.483 us; speedup 1.0000x reference)
//
#include <hip/hip_runtime.h>
#include <hip/hip_bf16.h>

// BranchTeacherLayoutLoss — 3 kernels:
//  1) row_norm: streaming pass over emb [N,256] -> per-row direction factor f[r]
//  2) gather_accum: shuffle-free gather; acc += emb[idx]*f[idx], segment-sorted
//     running accumulator flushed via atomics at boundaries (avg seg len ~390)
//  3) finalize: per-segment scalar epilogue
// Rationale (R2 post-mortem): gather was latency-bound because a 6-step
// dependent shuffle butterfly sat between each row load and its use. Moving
// the norm to a streaming pass makes the gather pure load+FMA (8-deep unroll),
// and leaves the 205 MB table hot in the 256 MB L3 for the gather pass.

constexpr int D = 256;          // feature dim (fixed by reference)
constexpr int CHUNK = 32;       // members per wave in gather pass
constexpr float MAXNORM = 1.0f - 1e-5f;

__device__ __forceinline__ float wave_reduce_add(float v) {
    #pragma unroll
    for (int off = 32; off >= 1; off >>= 1)
        v += __shfl_xor(v, off, 64);
    return v;
}

__device__ __forceinline__ float dir_factor(float ss) {
    const float norm  = sqrtf(ss);
    const float scale = (norm > MAXNORM) ? (MAXNORM / fmaxf(norm, 1e-12f)) : 1.0f;
    return scale / fmaxf(norm * scale, 1e-8f);   // direction = x * f
}

// ---- pass 1: per-row norm factors (streaming, 4 rows per wave) ----
__global__ void __launch_bounds__(256)
row_norm_kernel(const float* __restrict__ emb,
                float* __restrict__ fvec,
                int N) {
    const int wave = blockIdx.x * (blockDim.x >> 6) + (threadIdx.x >> 6);
    const int lane = threadIdx.x & 63;
    const int r0 = wave * 4;
    if (r0 >= N) return;

    if (r0 + 4 <= N) {
        const float4 v0 = *reinterpret_cast<const float4*>(emb + (size_t)(r0 + 0) * D + lane * 4);
        const float4 v1 = *reinterpret_cast<const float4*>(emb + (size_t)(r0 + 1) * D + lane * 4);
        const float4 v2 = *reinterpret_cast<const float4*>(emb + (size_t)(r0 + 2) * D + lane * 4);
        const float4 v3 = *reinterpret_cast<const float4*>(emb + (size_t)(r0 + 3) * D + lane * 4);
        float s[4];
        s[0] = v0.x * v0.x + v0.y * v0.y + v0.z * v0.z + v0.w * v0.w;
        s[1] = v1.x * v1.x + v1.y * v1.y + v1.z * v1.z + v1.w * v1.w;
        s[2] = v2.x * v2.x + v2.y * v2.y + v2.z * v2.z + v2.w * v2.w;
        s[3] = v3.x * v3.x + v3.y * v3.y + v3.z * v3.z + v3.w * v3.w;
        #pragma unroll
        for (int off = 32; off >= 1; off >>= 1) {
            #pragma unroll
            for (int j = 0; j < 4; ++j)
                s[j] += __shfl_xor(s[j], off, 64);   // 4 independent chains
        }
        if (lane == 0) {
            float4 f4 = make_float4(dir_factor(s[0]), dir_factor(s[1]),
                                    dir_factor(s[2]), dir_factor(s[3]));
            *reinterpret_cast<float4*>(fvec + r0) = f4;
        }
    } else {
        for (int r = r0; r < N; ++r) {
            const float4 v = *reinterpret_cast<const float4*>(emb + (size_t)r * D + lane * 4);
            float ss = v.x * v.x + v.y * v.y + v.z * v.z + v.w * v.w;
            ss = wave_reduce_add(ss);
            if (lane == 0) fvec[r] = dir_factor(ss);
        }
    }
}

// ---- pass 2: shuffle-free gather + segment accumulate ----
__global__ void __launch_bounds__(256)
gather_accum_kernel(const float* __restrict__ emb,
                    const float* __restrict__ fvec,
                    const int*   __restrict__ midx,
                    const int*   __restrict__ segid,
                    float* __restrict__ seg_sum,   // [B][D]
                    float* __restrict__ counts,    // [B]
                    int M) {
    const int wave = blockIdx.x * (blockDim.x >> 6) + (threadIdx.x >> 6);
    const int lane = threadIdx.x & 63;
    int m = wave * CHUNK;
    if (m >= M) return;
    const int mend = min(m + CHUNK, M);

    float4 acc = {0.f, 0.f, 0.f, 0.f};
    float  cnt = 0.f;
    int cur_seg = segid[m];

    while (m < mend) {
        if (m + 8 <= mend && segid[m + 7] == cur_seg) {
            // fast path: 8 members, all in cur_seg (sorted ids) -> 8 outstanding row loads
            int   idx[8];
            float ff[8];
            #pragma unroll
            for (int j = 0; j < 8; ++j) idx[j] = midx[m + j];          // wave-uniform
            #pragma unroll
            for (int j = 0; j < 8; ++j) ff[j] = fvec[idx[j]];          // broadcast, cached
            float4 v[8];
            #pragma unroll
            for (int j = 0; j < 8; ++j)
                v[j] = *reinterpret_cast<const float4*>(emb + (size_t)idx[j] * D + lane * 4);
            #pragma unroll
            for (int j = 0; j < 8; ++j) {
                acc.x += v[j].x * ff[j];
                acc.y += v[j].y * ff[j];
                acc.z += v[j].z * ff[j];
                acc.w += v[j].w * ff[j];
            }
            cnt += 8.f;
            m += 8;
        } else {
            const int seg = segid[m];
            if (seg != cur_seg) {
                float* dst = seg_sum + (size_t)cur_seg * D + lane * 4;
                atomicAdd(dst + 0, acc.x);
                atomicAdd(dst + 1, acc.y);
                atomicAdd(dst + 2, acc.z);
                atomicAdd(dst + 3, acc.w);
                if (lane == 0) atomicAdd(&counts[cur_seg], cnt);
                acc = {0.f, 0.f, 0.f, 0.f};
                cnt = 0.f;
                cur_seg = seg;
            }
            const int idx = midx[m];
            const float f = fvec[idx];
            const float4 v = *reinterpret_cast<const float4*>(emb + (size_t)idx * D + lane * 4);
            acc.x += v.x * f;
            acc.y += v.y * f;
            acc.z += v.z * f;
            acc.w += v.w * f;
            cnt += 1.f;
            m += 1;
        }
    }
    float* dst = seg_sum + (size_t)cur_seg * D + lane * 4;
    atomicAdd(dst + 0, acc.x);
    atomicAdd(dst + 1, acc.y);
    atomicAdd(dst + 2, acc.z);
    atomicAdd(dst + 3, acc.w);
    if (lane == 0) atomicAdd(&counts[cur_seg], cnt);
}

// ---- pass 3: per-segment epilogue ----
__global__ void __launch_bounds__(256)
finalize_kernel(const float* __restrict__ seg_sum,
                const float* __restrict__ counts,
                const float* __restrict__ tcent,
                const float* __restrict__ tcoh,
                float* __restrict__ out,
                int B) {
    const int seg  = blockIdx.x * (blockDim.x >> 6) + (threadIdx.x >> 6);
    const int lane = threadIdx.x & 63;
    if (seg >= B) return;

    const float4 s = *reinterpret_cast<const float4*>(seg_sum + (size_t)seg * D + lane * 4);
    const float  c = fmaxf(counts[seg], 1.0f);
    const float inv_c = 1.0f / c;
    float4 mean = {s.x * inv_c, s.y * inv_c, s.z * inv_c, s.w * inv_c};

    float ss = mean.x * mean.x + mean.y * mean.y + mean.z * mean.z + mean.w * mean.w;
    ss = wave_reduce_add(ss);                         // ||mean_raw||^2
    const float mnorm = sqrtf(ss);
    const float inv   = 1.0f / fmaxf(mnorm, 1e-12f);  // centroid = mean * inv

    const float4 t = *reinterpret_cast<const float4*>(tcent + (size_t)seg * D + lane * 4);
    float dt = mean.x * t.x + mean.y * t.y + mean.z * t.z + mean.w * t.w;
    dt = wave_reduce_add(dt) * inv;                   // <centroid, teacher>

    const float centroid_loss = 1.0f - dt;
    const float cohesion      = 1.0f - ss * inv;      // 1 - <mean_raw, centroid> = 1 - ||mean||
    const float coh_loss      = fmaxf(cohesion - tcoh[seg], 0.0f);

    if (lane == 0)
        atomicAdd(out, (centroid_loss + coh_loss) / (float)B);
}

extern "C" void kernel_launch(void* const* d_in, const int* in_sizes, int n_in,
                              void* d_out, int out_size, void* d_ws, size_t ws_size,
                              hipStream_t stream) {
    const float* emb   = (const float*)d_in[0];   // [N, 256]
    const float* tcent = (const float*)d_in[1];   // [B, 256]
    const float* tcoh  = (const float*)d_in[2];   // [B]
    const int*   midx  = (const int*)d_in[3];     // [M]
    const int*   segid = (const int*)d_in[4];     // [M]
    const int B = in_sizes[2];
    const int M = in_sizes[3];
    const int N = in_sizes[0] / D;

    float* seg_sum = (float*)d_ws;                    // B*D floats
    float* counts  = seg_sum + (size_t)B * D;         // B floats
    float* fvec    = counts + B;                      // N floats

    hipMemsetAsync(d_ws, 0, ((size_t)B * D + B) * sizeof(float), stream);
    hipMemsetAsync(d_out, 0, sizeof(float), stream);

    const int waves_per_block = 4;                    // 256 threads = 4 waves

    // pass 1: 4 rows per wave
    const int n_waves1 = (N + 3) / 4;
    const int blocks1  = (n_waves1 + waves_per_block - 1) / waves_per_block;
    row_norm_kernel<<<blocks1, 256, 0, stream>>>(emb, fvec, N);

    // pass 2
    const int n_waves2 = (M + CHUNK - 1) / CHUNK;
    const int blocks2  = (n_waves2 + waves_per_block - 1) / waves_per_block;
    gather_accum_kernel<<<blocks2, 256, 0, stream>>>(emb, fvec, midx, segid, seg_sum, counts, M);

    // pass 3
    const int blocks3 = (B + waves_per_block - 1) / waves_per_block;
    finalize_kernel<<<blocks3, 256, 0, stream>>>(seg_sum, counts, tcent, tcoh, (float*)d_out, B);
}